// Round 5
// baseline (280.991 us; speedup 1.0000x reference)
//
#include <hip/hip_runtime.h>
#include <hip/hip_bf16.h>
#include <stdint.h>

#define TLEN 480
#define NB 128
#define NC 256

typedef short bf16x8 __attribute__((ext_vector_type(8)));
typedef float f32x4 __attribute__((ext_vector_type(4)));
typedef unsigned short u16;
typedef unsigned int u32;

__device__ inline u16 f2bf(float f) {   // RNE, used for the A operator (built once)
    union { float f; uint32_t u; } v; v.f = f;
    uint32_t u = v.u;
    return (u16)((u + 0x7fffu + ((u >> 16) & 1u)) >> 16);
}

// pack two fp32 -> (bf16(hi)<<16)|bf16(lo) by truncation: one v_perm_b32
__device__ inline u32 pack2bf(float lo, float hi) {
    return __builtin_amdgcn_perm(__float_as_uint(hi), __float_as_uint(lo), 0x07060302u);
}

// degree-1 LOESS weights; Q compile-time -> full unroll, w[] in registers.
template<int N, int Q>
__device__ __forceinline__ int loess_wT(int t, float* out) {
    int left = t - (Q - 1) / 2;
    if (left < 0) left = 0;
    if (left > N - Q) left = N - Q;
    int right = left + Q - 1;
    int h = (t - left) > (right - t) ? (t - left) : (right - t);
    double w[Q];
    double wsum = 0.0;
    #pragma unroll
    for (int i = 0; i < Q; ++i) {
        double dist = fabs((double)(left + i - t)) / (double)h;
        double u = 1.0 - dist * dist * dist;
        if (u < 0.0) u = 0.0;
        double wv = u * u * u;
        w[i] = wv; wsum += wv;
    }
    #pragma unroll
    for (int i = 0; i < Q; ++i) w[i] /= wsum;
    double xbar = 0.0;
    #pragma unroll
    for (int i = 0; i < Q; ++i) xbar += w[i] * (double)(left + i);
    double var = 0.0;
    #pragma unroll
    for (int i = 0; i < Q; ++i) { double d = (double)(left + i) - xbar; var += w[i] * d * d; }
    if (var > 1e-12) {
        double tb = (double)t - xbar;
        #pragma unroll
        for (int i = 0; i < Q; ++i) {
            double d = (double)(left + i) - xbar;
            out[i] = (float)(w[i] * (1.0 + tb * d / var));
        }
    } else {
        #pragma unroll
        for (int i = 0; i < Q; ++i) out[i] = (float)w[i];
    }
    return left;
}

// Ms dense (34x32), MlpC (480x17 compact), MtC (480x29 compact), w3 (31-tap MA15*MA15*MA3)
__global__ void k_loess(float* Ms, float* w3, float* MlpC, float* MtC) {
    int gid = blockIdx.x * 256 + threadIdx.x;
    if (gid < 34) {
        float wl[7];
        int left = loess_wT<32, 7>(gid - 1, wl);
        float* row = Ms + gid * 32;
        #pragma unroll
        for (int i = 0; i < 32; ++i) row[i] = 0.0f;
        #pragma unroll
        for (int i = 0; i < 7; ++i) row[left + i] = wl[i];
    } else if (gid < 514) {
        int t = gid - 34;
        float wl[17];
        loess_wT<TLEN, 17>(t, wl);
        #pragma unroll
        for (int i = 0; i < 17; ++i) MlpC[t * 17 + i] = wl[i];
    } else if (gid < 994) {
        int t = gid - 514;
        float wl[29];
        loess_wT<TLEN, 29>(t, wl);
        #pragma unroll
        for (int i = 0; i < 29; ++i) MtC[t * 29 + i] = wl[i];
    } else if (gid < 1025) {
        int d = gid - 994;            // 0..30
        int cnt = 0;
        for (int c = 0; c < 3; ++c)
            for (int a = 0; a < 15; ++a) {
                int b = d - a - c;
                if (b >= 0 && b < 15) cnt++;
            }
        w3[d] = (float)((double)cnt / 675.0);
    }
}

// S[t][u] = Ecenter[t][u] - sum_{k<17} MlpC[t][k] * G[slp(t)+k][u]
__global__ void k_S(const float* __restrict__ Ms, const float* __restrict__ w3,
                    const float* __restrict__ MlpC, float* __restrict__ S) {
    int id = blockIdx.x * 256 + threadIdx.x;
    if (id >= TLEN * TLEN) return;
    int t = id / TLEN, u = id - t * TLEN;
    int nu = u / 15, ju = u - nu * 15;
    int slp = t - 8;
    if (slp < 0) slp = 0;
    if (slp > TLEN - 17) slp = TLEN - 17;
    float acc = 0.0f;
    for (int k = 0; k < 17; ++k) {
        int i = slp + k;
        int s_lo = (i - ju + 14) / 15;
        float g = 0.0f;
        #pragma unroll
        for (int ds = 0; ds < 3; ++ds) {
            int s = s_lo + ds;
            int d = s * 15 + ju - i;
            if (s >= 0 && s < 34 && d >= 0 && d <= 30)
                g += Ms[s * 32 + nu] * w3[d];
        }
        acc += MlpC[t * 17 + k] * g;
    }
    float val = -acc;
    if (t % 15 == ju) val += Ms[(1 + t / 15) * 32 + nu];
    S[id] = val;
}

// V = Mt @ S (banded 29), U = Mt - V (Mt from compact)
__global__ void k_VU(const float* __restrict__ MtC, const float* __restrict__ S,
                     float* __restrict__ U, float* __restrict__ V) {
    int id = blockIdx.x * 256 + threadIdx.x;
    if (id >= TLEN * TLEN) return;
    int t = id / TLEN, u = id - t * TLEN;
    int st = t - 14;
    if (st < 0) st = 0;
    if (st > TLEN - 29) st = TLEN - 29;
    float acc = 0.0f;
    for (int k = 0; k < 29; ++k)
        acc += MtC[t * 29 + k] * S[(size_t)(st + k) * TLEN + u];
    float mt = (u >= st && u < st + 29) ? MtC[t * 29 + (u - st)] : 0.0f;
    V[id] = acc;
    U[id] = mt - acc;
}

// A = U + V@U, output bf16 (RNE); 16x16 LDS-tiled fp32 matmul (480^3, tiny)
__global__ void k_A(const float* __restrict__ U, const float* __restrict__ V,
                    u16* __restrict__ Abf) {
    __shared__ float Vs[16][17];
    __shared__ float Us[16][17];
    int tx = threadIdx.x, ty = threadIdx.y;
    int u = blockIdx.x * 16 + tx;
    int t = blockIdx.y * 16 + ty;
    float acc = 0.0f;
    for (int kt = 0; kt < 30; ++kt) {
        Vs[ty][tx] = V[(size_t)t * TLEN + kt * 16 + tx];
        Us[ty][tx] = U[(size_t)(kt * 16 + ty) * TLEN + u];
        __syncthreads();
        #pragma unroll
        for (int e = 0; e < 16; ++e) acc += Vs[ty][e] * Us[e][tx];
        __syncthreads();
    }
    Abf[(size_t)t * TLEN + u] = f2bf(U[(size_t)t * TLEN + u] + acc);
}

// Fused transpose+GEMM: trend = A @ x_b^T per batch; out1 = trend, out0 = x - trend.
//
// v5 (registers back): v4's launch_bounds(256,5) capped VGPR at 48 and the compiler
// de-pipelined the kernel (prefetch buffers demoted -> serial L2/HBM round trips;
// 81 -> 100 us despite 2.4x occupancy).  v5 keeps the 32-c tile (minimal-conflict
// LDS maps, low FETCH) but relaxes to (256,4) => 128-VGPR budget, and spends it:
//   - staging: ALL 16 float4 loads issued up front (64 VGPR in flight), packed in
//     order afterwards -> ~1 HBM round trip instead of 4 dependent ones.
//   - B-operand (A-matrix rows, L2-hot): prefetch depth 2 via rotating 3-slot
//     buffer, all indices compile-time under full unroll (no scratch).
// Epilogue (LDS-transposed full-line nt stores) and bank maps unchanged from v4.
__global__ __launch_bounds__(256, 4)
void k_gemm(const u16* __restrict__ A, const float* __restrict__ x,
            float* __restrict__ out0, float* __restrict__ out1) {
    __shared__ u16 Xs[32 * 488];     // 31,232 B
    int b = blockIdx.x;
    int t0 = blockIdx.y * 96;
    int cz = blockIdx.z * 32;
    int tid = threadIdx.x;
    int wave = tid >> 6, lane = tid & 63;
    int lane15 = lane & 15, quad = lane >> 4;
    int wt = wave & 1, wc = wave >> 1;   // wave tile: 16c x 48t

    // ---- staging: x[b, 0:480, cz:cz+32] -> LDS bf16 [c][488] ----
    int cq  = tid & 7;       // c-quad (4 c's)
    int kq0 = tid >> 3;      // k-quad (4 k's); pass covers 128 k
    const float* xp0 = x + (size_t)b * TLEN * NC + (size_t)(kq0 * 4) * NC + cz + cq * 4;
    u32* l32 = (u32*)Xs;
    int lbase = (cq * 4) * 244 + kq0 * 2;     // u32; +244/channel, +64/pass

    float4 r[16];
    #pragma unroll
    for (int p = 0; p < 4; ++p) {
        if (p < 3 || kq0 < 24) {       // tail: pass 3 covers rows 384..479 only
            const float* xp = xp0 + (size_t)p * 128 * NC;
            #pragma unroll
            for (int q = 0; q < 4; ++q) r[p * 4 + q] = *(const float4*)(xp + q * NC);
        }
    }
    #pragma unroll
    for (int p = 0; p < 4; ++p) {
        if (p < 3 || kq0 < 24) {
            const float* fl = (const float*)&r[p * 4];   // [q*4 + cc], compile-time indexed
            int o = lbase + p * 64;
            #pragma unroll
            for (int cc = 0; cc < 4; ++cc) {
                uint2 w;
                w.x = pack2bf(fl[0 * 4 + cc], fl[1 * 4 + cc]);
                w.y = pack2bf(fl[2 * 4 + cc], fl[3 * 4 + cc]);
                *(uint2*)(l32 + o + cc * 244) = w;
            }
        }
    }
    __syncthreads();   // barrier #1: LDS x-tile complete

    // ---- compute: 15 k-steps, B prefetch depth 2, A (LDS) depth 1, no barriers ----
    const u16* bp0 = A + (size_t)(t0 + wt * 48 + lane15) * TLEN + quad * 8;
    int arow = (wc * 16 + lane15) * 488 + quad * 8;    // u16 index into Xs

    f32x4 acc[3] = {};
    bf16x8 B[3][3];        // [slot][j], slot = k-step % 3
    bf16x8 Af[2];          // [k-step & 1]
    #pragma unroll
    for (int j = 0; j < 3; ++j) {
        B[0][j] = *(const bf16x8*)(bp0 + (size_t)j * 16 * TLEN);
        B[1][j] = *(const bf16x8*)(bp0 + (size_t)j * 16 * TLEN + 32);
    }
    Af[0] = *(const bf16x8*)&Xs[arow];

    #pragma unroll
    for (int s = 0; s < 15; ++s) {
        const int cs = s % 3;              // compile-time under full unroll
        const int ns = (s + 2) % 3;
        const int pa = s & 1, na = (s & 1) ^ 1;
        if (s < 13) {
            int k = (s + 2) * 32;
            #pragma unroll
            for (int j = 0; j < 3; ++j)
                B[ns][j] = *(const bf16x8*)(bp0 + (size_t)j * 16 * TLEN + k);
        }
        if (s < 14)
            Af[na] = *(const bf16x8*)&Xs[arow + (s + 1) * 32];
        #pragma unroll
        for (int j = 0; j < 3; ++j)
            acc[j] = __builtin_amdgcn_mfma_f32_16x16x32_bf16(Af[pa], B[cs][j], acc[j], 0, 0, 0);
    }

    __syncthreads();   // barrier #2: everyone done reading Xs; safe to alias

    // ---- epilogue: acc -> LDS fp32 [96][36] (x2 tensors), then line-complete stores ----
    float* T = (float*)Xs;          // trend  [96][36] = 13,824 B
    float* R = T + 96 * 36;         // resid  [96][36]; total 27,648 <= 31,232
    #pragma unroll
    for (int j = 0; j < 3; ++j) {
        int tl = wt * 48 + j * 16 + lane15;
        int clb = wc * 16 + quad * 4;
        f32x4 tv = acc[j];
        size_t gb = ((size_t)b * TLEN + t0 + tl) * NC + cz + clb;
        f32x4 xv = *(const f32x4*)(x + gb);
        *(f32x4*)&T[tl * 36 + clb] = tv;
        *(f32x4*)&R[tl * 36 + clb] = xv - tv;
    }
    __syncthreads();   // barrier #3

    #pragma unroll
    for (int v = 0; v < 3; ++v) {
        int id = v * 256 + tid;
        int tl = id >> 3, c4 = (id & 7) * 4;
        size_t gb = ((size_t)b * TLEN + t0 + tl) * NC + cz + c4;
        f32x4 tv = *(const f32x4*)&T[tl * 36 + c4];
        f32x4 rv = *(const f32x4*)&R[tl * 36 + c4];
        __builtin_nontemporal_store(tv, (f32x4*)(out1 + gb));
        __builtin_nontemporal_store(rv, (f32x4*)(out0 + gb));
    }
}

extern "C" void kernel_launch(void* const* d_in, const int* in_sizes, int n_in,
                              void* d_out, int out_size, void* d_ws, size_t ws_size,
                              hipStream_t stream) {
    const float* x = (const float*)d_in[0];
    float* out0 = (float*)d_out;                           // seasonal + resid = x - trend
    float* out1 = (float*)d_out + (size_t)NB * TLEN * NC;  // trend

    char* ws = (char*)d_ws;
    size_t oMs  = 0;                       // 34*32*4 = 4352
    size_t oW3  = oMs + 4352;              // 128
    size_t oLpC = oW3 + 128;               // 480*17*4 = 32640
    size_t oMtC = oLpC + 32640;            // 480*29*4 = 55680
    size_t oS   = oMtC + 55680;            // 921600
    size_t oU   = oS + 921600;
    size_t oV   = oU + 921600;
    size_t oA   = oV + 921600;             // bf16 460800

    float* Ms   = (float*)(ws + oMs);
    float* w3   = (float*)(ws + oW3);
    float* MlpC = (float*)(ws + oLpC);
    float* MtC  = (float*)(ws + oMtC);
    float* S    = (float*)(ws + oS);
    float* U    = (float*)(ws + oU);
    float* V    = (float*)(ws + oV);
    u16*   Abf  = (u16*)(ws + oA);

    k_loess<<<5, 256, 0, stream>>>(Ms, w3, MlpC, MtC);
    k_S<<<900, 256, 0, stream>>>(Ms, w3, MlpC, S);
    k_VU<<<900, 256, 0, stream>>>(MtC, S, U, V);
    k_A<<<dim3(30, 30), dim3(16, 16), 0, stream>>>(U, V, Abf);
    k_gemm<<<dim3(NB, 5, 8), 256, 0, stream>>>(Abf, x, out0, out1);
}

// Round 6
// 271.701 us; speedup vs baseline: 1.0342x; 1.0342x over previous
//
#include <hip/hip_runtime.h>
#include <hip/hip_bf16.h>
#include <stdint.h>

#define TLEN 480
#define NB 128
#define NC 256

typedef short bf16x8 __attribute__((ext_vector_type(8)));
typedef float f32x4 __attribute__((ext_vector_type(4)));
typedef unsigned short u16;
typedef unsigned int u32;

__device__ inline u16 f2bf(float f) {   // RNE, used for the A operator (built once)
    union { float f; uint32_t u; } v; v.f = f;
    uint32_t u = v.u;
    return (u16)((u + 0x7fffu + ((u >> 16) & 1u)) >> 16);
}

// pack two fp32 -> (bf16(hi)<<16)|bf16(lo) by truncation: one v_perm_b32
__device__ inline u32 pack2bf(float lo, float hi) {
    return __builtin_amdgcn_perm(__float_as_uint(hi), __float_as_uint(lo), 0x07060302u);
}

// async 16B global->LDS (direct-to-shared DMA; compiler cannot sink this)
__device__ __forceinline__ void glds16(const void* g, void* l) {
    __builtin_amdgcn_global_load_lds(
        (const __attribute__((address_space(1))) unsigned int*)g,
        (__attribute__((address_space(3))) unsigned int*)l,
        16, 0, 0);
}

// degree-1 LOESS weights; Q compile-time -> full unroll, w[] in registers.
template<int N, int Q>
__device__ __forceinline__ int loess_wT(int t, float* out) {
    int left = t - (Q - 1) / 2;
    if (left < 0) left = 0;
    if (left > N - Q) left = N - Q;
    int right = left + Q - 1;
    int h = (t - left) > (right - t) ? (t - left) : (right - t);
    double w[Q];
    double wsum = 0.0;
    #pragma unroll
    for (int i = 0; i < Q; ++i) {
        double dist = fabs((double)(left + i - t)) / (double)h;
        double u = 1.0 - dist * dist * dist;
        if (u < 0.0) u = 0.0;
        double wv = u * u * u;
        w[i] = wv; wsum += wv;
    }
    #pragma unroll
    for (int i = 0; i < Q; ++i) w[i] /= wsum;
    double xbar = 0.0;
    #pragma unroll
    for (int i = 0; i < Q; ++i) xbar += w[i] * (double)(left + i);
    double var = 0.0;
    #pragma unroll
    for (int i = 0; i < Q; ++i) { double d = (double)(left + i) - xbar; var += w[i] * d * d; }
    if (var > 1e-12) {
        double tb = (double)t - xbar;
        #pragma unroll
        for (int i = 0; i < Q; ++i) {
            double d = (double)(left + i) - xbar;
            out[i] = (float)(w[i] * (1.0 + tb * d / var));
        }
    } else {
        #pragma unroll
        for (int i = 0; i < Q; ++i) out[i] = (float)w[i];
    }
    return left;
}

// Ms dense (34x32), MlpC (480x17 compact), MtC (480x29 compact), w3 (31-tap MA15*MA15*MA3)
__global__ void k_loess(float* Ms, float* w3, float* MlpC, float* MtC) {
    int gid = blockIdx.x * 256 + threadIdx.x;
    if (gid < 34) {
        float wl[7];
        int left = loess_wT<32, 7>(gid - 1, wl);
        float* row = Ms + gid * 32;
        #pragma unroll
        for (int i = 0; i < 32; ++i) row[i] = 0.0f;
        #pragma unroll
        for (int i = 0; i < 7; ++i) row[left + i] = wl[i];
    } else if (gid < 514) {
        int t = gid - 34;
        float wl[17];
        loess_wT<TLEN, 17>(t, wl);
        #pragma unroll
        for (int i = 0; i < 17; ++i) MlpC[t * 17 + i] = wl[i];
    } else if (gid < 994) {
        int t = gid - 514;
        float wl[29];
        loess_wT<TLEN, 29>(t, wl);
        #pragma unroll
        for (int i = 0; i < 29; ++i) MtC[t * 29 + i] = wl[i];
    } else if (gid < 1025) {
        int d = gid - 994;            // 0..30
        int cnt = 0;
        for (int c = 0; c < 3; ++c)
            for (int a = 0; a < 15; ++a) {
                int b = d - a - c;
                if (b >= 0 && b < 15) cnt++;
            }
        w3[d] = (float)((double)cnt / 675.0);
    }
}

// S[t][u] = Ecenter[t][u] - sum_{k<17} MlpC[t][k] * G[slp(t)+k][u]
__global__ void k_S(const float* __restrict__ Ms, const float* __restrict__ w3,
                    const float* __restrict__ MlpC, float* __restrict__ S) {
    int id = blockIdx.x * 256 + threadIdx.x;
    if (id >= TLEN * TLEN) return;
    int t = id / TLEN, u = id - t * TLEN;
    int nu = u / 15, ju = u - nu * 15;
    int slp = t - 8;
    if (slp < 0) slp = 0;
    if (slp > TLEN - 17) slp = TLEN - 17;
    float acc = 0.0f;
    for (int k = 0; k < 17; ++k) {
        int i = slp + k;
        int s_lo = (i - ju + 14) / 15;
        float g = 0.0f;
        #pragma unroll
        for (int ds = 0; ds < 3; ++ds) {
            int s = s_lo + ds;
            int d = s * 15 + ju - i;
            if (s >= 0 && s < 34 && d >= 0 && d <= 30)
                g += Ms[s * 32 + nu] * w3[d];
        }
        acc += MlpC[t * 17 + k] * g;
    }
    float val = -acc;
    if (t % 15 == ju) val += Ms[(1 + t / 15) * 32 + nu];
    S[id] = val;
}

// V = Mt @ S (banded 29), U = Mt - V (Mt from compact)
__global__ void k_VU(const float* __restrict__ MtC, const float* __restrict__ S,
                     float* __restrict__ U, float* __restrict__ V) {
    int id = blockIdx.x * 256 + threadIdx.x;
    if (id >= TLEN * TLEN) return;
    int t = id / TLEN, u = id - t * TLEN;
    int st = t - 14;
    if (st < 0) st = 0;
    if (st > TLEN - 29) st = TLEN - 29;
    float acc = 0.0f;
    for (int k = 0; k < 29; ++k)
        acc += MtC[t * 29 + k] * S[(size_t)(st + k) * TLEN + u];
    float mt = (u >= st && u < st + 29) ? MtC[t * 29 + (u - st)] : 0.0f;
    V[id] = acc;
    U[id] = mt - acc;
}

// A = U + V@U, output bf16 (RNE); 16x16 LDS-tiled fp32 matmul (480^3, tiny)
__global__ void k_A(const float* __restrict__ U, const float* __restrict__ V,
                    u16* __restrict__ Abf) {
    __shared__ float Vs[16][17];
    __shared__ float Us[16][17];
    int tx = threadIdx.x, ty = threadIdx.y;
    int u = blockIdx.x * 16 + tx;
    int t = blockIdx.y * 16 + ty;
    float acc = 0.0f;
    for (int kt = 0; kt < 30; ++kt) {
        Vs[ty][tx] = V[(size_t)t * TLEN + kt * 16 + tx];
        Us[ty][tx] = U[(size_t)(kt * 16 + ty) * TLEN + u];
        __syncthreads();
        #pragma unroll
        for (int e = 0; e < 16; ++e) acc += Vs[ty][e] * Us[e][tx];
        __syncthreads();
    }
    Abf[(size_t)t * TLEN + u] = f2bf(U[(size_t)t * TLEN + u] + acc);
}

// Fused transpose+GEMM: trend = A @ x_b^T per batch; out1 = trend, out0 = x - trend.
//
// v6 (both operands from LDS; chunked-K, m97-style pacing): grid (b, 5 t-tiles
// of 96, 4 c-slices of 64), 2560 blocks, 4 waves, wave tile 32c x 48t (6 MFMA
// per k-step -- v3's amortization, which beat v4/v5's 3).  Per k-step (BK=32):
//   - A-matrix chunk [96t][32k] bf16 (6 KB) staged GLOBAL->LDS DIRECT via
//     global_load_lds dwordx4 (6 insts/chunk, linear dest, L2-resident src).
//     The compiler cannot sink these; the per-step barrier's vmcnt(0) drain is
//     the pacing (m97 structure).  B-frags now come from LDS -> NO dependent
//     global loads in the consume path (v3-v5's invariant ~300cy/step stall).
//   - x chunk [64c][32k] bf16 (5 KB +pad) staged with lead-2 register
//     pack-transpose (loads for step s+2 issued in interval s).
// Both double-buffered; ONE barrier per step.  LDS 25.5 KB -> 6 blocks/CU of
// stagger to cover each block's barrier-drain.  All LDS maps at the wave64
// structural minimum (pack-writes 2/bank; all b128 reads exact 8-cycle tiles;
// glds dest linear).  Epilogue: acc -> LDS fp32 [96][68] (aliases staging
// buffers after last barrier), then full-line nt stores; x re-read at the
// store mapping (coalesced) so a single LDS tensor suffices.
__global__ __launch_bounds__(256, 4)
void k_gemm(const u16* __restrict__ A, const float* __restrict__ x,
            float* __restrict__ out0, float* __restrict__ out1) {
    __shared__ __align__(16) char lds_raw[26112];   // max(staging 22528, epi 26112)
    u16* xbuf = (u16*)lds_raw;            // 2 x [64][40] u16 = 10240 B
    u16* abuf = (u16*)(lds_raw + 10240);  // 2 x [96][32] u16 = 12288 B

    int b = blockIdx.x;
    int t0 = blockIdx.y * 96;
    int cz = blockIdx.z * 64;
    int tid = threadIdx.x;
    int wave = tid >> 6, lane = tid & 63;
    int lane15 = lane & 15, quad = lane >> 4;
    int wc = wave & 1, wt = wave >> 1;     // wave tile: 32c x 48t

    // x staging role: thread = (k-pair kk2, c-quad cq); chunk = 32k x 64c fp32
    int kk2 = tid & 15;                    // k-pair (2 k's)
    int cq  = tid >> 4;                    // c-quad (4 c's)
    const float* xg = x + (size_t)b * TLEN * NC + cz + cq * 4;

    // A staging role (glds): lane -> (row lrow, 16B-chunk lcol) of a 16-row slab
    int lrow = lane >> 2, lcol = lane & 3;
    const u16* ag = A + (size_t)(t0 + lrow) * TLEN + lcol * 8;

    float4 rs[2][2];   // two lead sets x two k-rows

    #define XLOAD(dst, s) { const float* p_ = xg + (size_t)((s) * 32 + 2 * kk2) * NC; \
        dst[0] = *(const float4*)p_; dst[1] = *(const float4*)(p_ + NC); }
    #define XPACK(src, h) { u32* o_ = (u32*)(xbuf + (h) * 2560); int bo_ = cq * 80 + kk2; \
        o_[bo_]      = pack2bf(src[0].x, src[1].x); \
        o_[bo_ + 20] = pack2bf(src[0].y, src[1].y); \
        o_[bo_ + 40] = pack2bf(src[0].z, src[1].z); \
        o_[bo_ + 60] = pack2bf(src[0].w, src[1].w); }
    #define ASTAGE(s, h) { \
        glds16(ag + (size_t)(wave * 16) * TLEN + (s) * 32, abuf + (h) * 3072 + wave * 512); \
        if (wave < 2) \
            glds16(ag + (size_t)((wave + 4) * 16) * TLEN + (s) * 32, abuf + (h) * 3072 + (wave + 4) * 512); }

    // prologue: step0 A->LDS(0), x step0 packed to LDS(0), x step1 in regs
    XLOAD(rs[0], 0);
    ASTAGE(0, 0);
    XLOAD(rs[1], 1);
    XPACK(rs[0], 0);
    __syncthreads();   // drains glds(0) + x loads

    f32x4 acc[2][3] = {};
    #pragma unroll
    for (int s = 0; s < 15; ++s) {
        const int cur = s & 1, nxt = cur ^ 1;
        if (s < 14) {
            ASTAGE(s + 1, nxt);                       // A chunk s+1 -> other half
            if (s < 13) XLOAD(rs[s & 1], s + 2);      // x loads lead-2
            XPACK(rs[(s + 1) & 1], nxt);              // x chunk s+1 -> other half
        }
        // consume step s: all operands from LDS
        const u32* xb = (const u32*)xbuf + cur * 1280 + (wc * 32 + lane15) * 20 + quad * 4;
        bf16x8 a0 = *(const bf16x8*)xb;
        bf16x8 a1 = *(const bf16x8*)(xb + 320);       // +16 c rows
        const u16* ab = abuf + cur * 3072 + (wt * 48 + lane15) * 32 + quad * 8;
        #pragma unroll
        for (int j = 0; j < 3; ++j) {
            bf16x8 bb = *(const bf16x8*)(ab + j * 512);
            acc[0][j] = __builtin_amdgcn_mfma_f32_16x16x32_bf16(a0, bb, acc[0][j], 0, 0, 0);
            acc[1][j] = __builtin_amdgcn_mfma_f32_16x16x32_bf16(a1, bb, acc[1][j], 0, 0, 0);
        }
        __syncthreads();   // drains next step's glds + pack writes; one barrier/step
    }
    #undef XLOAD
    #undef XPACK
    #undef ASTAGE

    // epilogue: acc -> LDS fp32 [96][68] (aliases staging; last barrier passed)
    float* T = (float*)lds_raw;
    #pragma unroll
    for (int i = 0; i < 2; ++i)
        #pragma unroll
        for (int j = 0; j < 3; ++j) {
            int tl = wt * 48 + j * 16 + lane15;
            int cl = wc * 32 + i * 16 + quad * 4;
            *(f32x4*)&T[tl * 68 + cl] = acc[i][j];
        }
    __syncthreads();

    #pragma unroll
    for (int v = 0; v < 6; ++v) {
        int id = v * 256 + tid;
        int tl = id >> 4, c4 = (id & 15) * 4;
        size_t gb = ((size_t)b * TLEN + t0 + tl) * NC + cz + c4;
        f32x4 tv = *(const f32x4*)&T[tl * 68 + c4];
        f32x4 xv = *(const f32x4*)(x + gb);
        __builtin_nontemporal_store(tv, (f32x4*)(out1 + gb));
        __builtin_nontemporal_store(xv - tv, (f32x4*)(out0 + gb));
    }
}

extern "C" void kernel_launch(void* const* d_in, const int* in_sizes, int n_in,
                              void* d_out, int out_size, void* d_ws, size_t ws_size,
                              hipStream_t stream) {
    const float* x = (const float*)d_in[0];
    float* out0 = (float*)d_out;                           // seasonal + resid = x - trend
    float* out1 = (float*)d_out + (size_t)NB * TLEN * NC;  // trend

    char* ws = (char*)d_ws;
    size_t oMs  = 0;                       // 34*32*4 = 4352
    size_t oW3  = oMs + 4352;              // 128
    size_t oLpC = oW3 + 128;               // 480*17*4 = 32640
    size_t oMtC = oLpC + 32640;            // 480*29*4 = 55680
    size_t oS   = oMtC + 55680;            // 921600
    size_t oU   = oS + 921600;
    size_t oV   = oU + 921600;
    size_t oA   = oV + 921600;             // bf16 460800

    float* Ms   = (float*)(ws + oMs);
    float* w3   = (float*)(ws + oW3);
    float* MlpC = (float*)(ws + oLpC);
    float* MtC  = (float*)(ws + oMtC);
    float* S    = (float*)(ws + oS);
    float* U    = (float*)(ws + oU);
    float* V    = (float*)(ws + oV);
    u16*   Abf  = (u16*)(ws + oA);

    k_loess<<<5, 256, 0, stream>>>(Ms, w3, MlpC, MtC);
    k_S<<<900, 256, 0, stream>>>(Ms, w3, MlpC, S);
    k_VU<<<900, 256, 0, stream>>>(MtC, S, U, V);
    k_A<<<dim3(30, 30), dim3(16, 16), 0, stream>>>(U, V, Abf);
    k_gemm<<<dim3(NB, 5, 4), 256, 0, stream>>>(Abf, x, out0, out1);
}